// Round 1
// baseline (12316.167 us; speedup 1.0000x reference)
//
#include <hip/hip_runtime.h>
#include <hip/hip_bf16.h>

// LSTM persistent kernel. B=128, T=1024, V=256, H=512, G=4H=2048.
// Decomposition: 4 batch groups (32 rows) x 64 gate slices (8 h-elems = 32 gate rows)
// = 256 workgroups, 256 threads (4 waves) each, all co-resident.
// Per step: gates = h @ W_hh^T via mfma_f32_16x16x32_bf16 (M=32,N=32,K=512),
// W_hh slice persistent in VGPR B-fragments; cell update fp32; h published bf16
// via agent-scope atomics + per-slice flags (ping-pong buffers).

#define TT 1024
#define BB 128
#define HH 512
#define VV 256

typedef __attribute__((ext_vector_type(8))) short short8;
typedef __attribute__((ext_vector_type(4))) float f32x4;

__device__ __forceinline__ unsigned short f2bf(float f) {
  __hip_bfloat16 h = __float2bfloat16(f);
  return *reinterpret_cast<unsigned short*>(&h);
}
__device__ __forceinline__ float sigm(float x) { return 1.0f / (1.0f + __expf(-x)); }
__device__ __forceinline__ float tanh_(float x) { return 1.0f - 2.0f / (1.0f + __expf(2.0f * x)); }

__global__ void lstm_init(const int* __restrict__ x, int* __restrict__ x_t,
                          unsigned int* __restrict__ hbuf0, int* __restrict__ flags) {
  int idx = blockIdx.x * 256 + threadIdx.x;  // 0..131071
  int t = idx >> 7, b = idx & 127;
  x_t[idx] = x[b * TT + t];                  // transpose for coalesced per-step reads
  if (idx < 32768) hbuf0[idx] = 0u;          // zero h version 0 (128KB bf16)
  if (idx < 256) flags[idx] = 0;             // version counters
}

__launch_bounds__(256)
__global__ void lstm_persist(const int* __restrict__ x_t, const int* __restrict__ x_len,
                             const float* __restrict__ W_ih, const float* __restrict__ W_hh,
                             const float* __restrict__ b_ih, const float* __restrict__ b_hh,
                             float* __restrict__ out,
                             unsigned short* __restrict__ hbuf,  // [2][128][512] bf16 bits
                             int* __restrict__ flags) {          // [4][64]
  const int tid = threadIdx.x;
  const int wave = tid >> 6, lane = tid & 63;
  const int wg = blockIdx.x;
  const int ib = wg >> 6;  // batch group 0..3
  const int ig = wg & 63;  // gate slice 0..63

  __shared__ float Wih_s[32 * 257];   // [32 gate rows][256 vocab], +1 pad stride
  __shared__ float bias_s[32];
  __shared__ float gates_s[32 * 33];  // [32 batch][32 gates], +1 pad stride
  __shared__ unsigned long long hstage[64];  // 32 rows x 8 bf16

  // ---- preload W_ih slice + bias into LDS ----
  {
    int lg = tid >> 3;   // 0..31  (q = lg>>3 in {i,f,g,o}, jj = lg&7)
    int seg = tid & 7;
    int grow = (lg >> 3) * HH + ig * 8 + (lg & 7);
    const float* src = W_ih + grow * VV;
    float* dst = Wih_s + lg * 257;
    for (int c2 = seg; c2 < VV; c2 += 8) dst[c2] = src[c2];
    if (tid < 32) {
      int g2 = (tid >> 3) * HH + ig * 8 + (tid & 7);
      bias_s[tid] = b_ih[g2] + b_hh[g2];
    }
  }

  // ---- persistent W_hh B-fragments (bf16) in registers ----
  const int Mtile = wave & 1, Ntile = wave >> 1;
  const int nn = lane & 15, quad = lane >> 4;
  short8 bw[16];
  {
    int lg = Ntile * 16 + nn;
    int grow = (lg >> 3) * HH + ig * 8 + (lg & 7);
    const float* src = W_hh + grow * HH + quad * 8;
#pragma unroll
    for (int kt = 0; kt < 16; kt++) {
      const float* s = src + kt * 32;
      short8 v;
#pragma unroll
      for (int j = 0; j < 8; j++) v[j] = (short)f2bf(s[j]);
      bw[kt] = v;
    }
  }

  // ---- per-thread cell state: thread = (batch row, h elem) ----
  const int bcell = tid >> 3, jj = tid & 7;
  const int bg_cell = ib * 32 + bcell;
  const int xl = x_len[bg_cell];
  float cst = 0.0f, hst = 0.0f;
  const int arow = ib * 32 + Mtile * 16 + (lane & 15);  // batch row for A frags
  int* myflags = flags + ib * 64;
  __syncthreads();

  for (int t = 0; t < TT; ++t) {
    const int p = t & 1;
    // 1. wait until all 64 slices of our batch group published version t
    if (wave == 0) {
      while (true) {
        int v = __hip_atomic_load(&myflags[lane], __ATOMIC_RELAXED, __HIP_MEMORY_SCOPE_AGENT);
        if (__all(v >= t)) break;
        __builtin_amdgcn_s_sleep(1);
      }
    }
    __syncthreads();
    __builtin_amdgcn_fence(__ATOMIC_ACQUIRE, "agent");  // inv L1/L2 so plain loads are fresh

    // 2. gates = h @ W_hh^T  (per wave: one 16x16 M-tile x one 16-col N-tile, K=512)
    const unsigned short* hsrc = hbuf + p * 65536 + arow * HH + quad * 8;
    short8 a[16];
#pragma unroll
    for (int kt = 0; kt < 16; kt++) a[kt] = *(const short8*)(hsrc + kt * 32);
    f32x4 acc = {0.f, 0.f, 0.f, 0.f};
#pragma unroll
    for (int kt = 0; kt < 16; kt++)
      acc = __builtin_amdgcn_mfma_f32_16x16x32_bf16(a[kt], bw[kt], acc, 0, 0, 0);
    {
      int row0 = Mtile * 16 + quad * 4;
      int col = Ntile * 16 + nn;
#pragma unroll
      for (int r = 0; r < 4; r++) gates_s[(row0 + r) * 33 + col] = acc[r];
    }
    __syncthreads();

    // 3. cell update (fp32): proj gather from LDS W_ih + bias, activations, mask
    {
      const int xv = x_t[t * BB + bg_cell];
      float g0 = gates_s[bcell * 33 + jj]      + Wih_s[jj * 257 + xv]        + bias_s[jj];
      float g1 = gates_s[bcell * 33 + 8 + jj]  + Wih_s[(8 + jj) * 257 + xv]  + bias_s[8 + jj];
      float g2 = gates_s[bcell * 33 + 16 + jj] + Wih_s[(16 + jj) * 257 + xv] + bias_s[16 + jj];
      float g3 = gates_s[bcell * 33 + 24 + jj] + Wih_s[(24 + jj) * 257 + xv] + bias_s[24 + jj];
      float iv = sigm(g0), fv = sigm(g1), gv = tanh_(g2), ov = sigm(g3);
      float cn = fv * cst + iv * gv;
      float hn = ov * tanh_(cn);
      bool act = (t < xl);
      if (act) { cst = cn; hst = hn; }
      out[(size_t)bg_cell * (TT * HH) + t * HH + ig * 8 + jj] = act ? hn : 0.0f;
      reinterpret_cast<unsigned short*>(hstage)[bcell * 8 + jj] = f2bf(hst);
    }
    __syncthreads();

    // 4. publish h slice (version t+1) to the other ping-pong buffer, then flag
    if (tid < 64) {
      unsigned long long v = hstage[tid];
      unsigned long long* dst = reinterpret_cast<unsigned long long*>(hbuf)
          + (size_t)(p ^ 1) * 16384 + (size_t)(ib * 32 + (tid >> 1)) * 128 + ig * 2 + (tid & 1);
      __hip_atomic_exchange(dst, v, __ATOMIC_RELAXED, __HIP_MEMORY_SCOPE_AGENT);
      asm volatile("s_waitcnt vmcnt(0)" ::: "memory");
      if (tid == 0)
        __hip_atomic_exchange(&myflags[ig], t + 1, __ATOMIC_RELAXED, __HIP_MEMORY_SCOPE_AGENT);
    }
  }

  // finals: h_T, c_T (fp32)
  out[(size_t)(BB * TT * HH) + (size_t)bg_cell * HH + ig * 8 + jj] = hst;
  out[(size_t)(BB * TT * HH) + BB * HH + (size_t)bg_cell * HH + ig * 8 + jj] = cst;
}

extern "C" void kernel_launch(void* const* d_in, const int* in_sizes, int n_in,
                              void* d_out, int out_size, void* d_ws, size_t ws_size,
                              hipStream_t stream) {
  const int*   x     = (const int*)d_in[0];    // [128][1024]
  const int*   x_len = (const int*)d_in[1];    // [128]
  const float* W_ih  = (const float*)d_in[2];  // [2048][256]
  const float* W_hh  = (const float*)d_in[3];  // [2048][512]
  const float* b_ih  = (const float*)d_in[4];  // [2048]
  const float* b_hh  = (const float*)d_in[5];  // [2048]
  float* out = (float*)d_out;

  char* ws = (char*)d_ws;
  int* x_t = (int*)ws;                                        // 524288 B
  unsigned short* hbuf = (unsigned short*)(ws + 524288);      // 262144 B (2x h ping-pong)
  int* flags = (int*)(ws + 524288 + 262144);                  // 1024 B

  lstm_init<<<512, 256, 0, stream>>>(x, x_t, (unsigned int*)hbuf, flags);
  lstm_persist<<<256, 256, 0, stream>>>(x_t, x_len, W_ih, W_hh, b_ih, b_hh, out, hbuf, flags);
}